// Round 1
// baseline (1653.880 us; speedup 1.0000x reference)
//
#include <hip/hip_runtime.h>
#include <stdint.h>
#include <math.h>

// ---------- float <-> monotonic uint key (for atomic min/max on floats) ----------
__device__ __forceinline__ uint32_t f2key(float f){
    uint32_t u = __float_as_uint(f);
    return (u & 0x80000000u) ? ~u : (u | 0x80000000u);
}
__device__ __forceinline__ float key2f(uint32_t k){
    uint32_t u = (k & 0x80000000u) ? (k ^ 0x80000000u) : ~k;
    return __uint_as_float(u);
}

// ws layout: [0 .. 65535] uint32 joint histogram; [65536 .. 65539] minmax keys
// keys: mm[0]=min_x, mm[1]=max_x, mm[2]=min_y, mm[3]=max_y

__global__ void init_mm_kernel(uint32_t* __restrict__ mm){
    mm[0] = 0xFFFFFFFFu;  // +inf key for min
    mm[1] = 0u;           // -inf key for max
    mm[2] = 0xFFFFFFFFu;
    mm[3] = 0u;
}

__global__ void minmax_kernel(const float4* __restrict__ x, const float4* __restrict__ y,
                              uint32_t* __restrict__ mm, int n4){
    float mnx =  INFINITY, mxx = -INFINITY;
    float mny =  INFINITY, mxy = -INFINITY;
    int stride = gridDim.x * blockDim.x;
    for (int i = blockIdx.x * blockDim.x + threadIdx.x; i < n4; i += stride){
        float4 a = x[i];
        float4 b = y[i];
        mnx = fminf(mnx, fminf(fminf(a.x, a.y), fminf(a.z, a.w)));
        mxx = fmaxf(mxx, fmaxf(fmaxf(a.x, a.y), fmaxf(a.z, a.w)));
        mny = fminf(mny, fminf(fminf(b.x, b.y), fminf(b.z, b.w)));
        mxy = fmaxf(mxy, fmaxf(fmaxf(b.x, b.y), fmaxf(b.z, b.w)));
    }
    // wave-64 shuffle reduce
    #pragma unroll
    for (int off = 32; off > 0; off >>= 1){
        mnx = fminf(mnx, __shfl_down(mnx, off, 64));
        mxx = fmaxf(mxx, __shfl_down(mxx, off, 64));
        mny = fminf(mny, __shfl_down(mny, off, 64));
        mxy = fmaxf(mxy, __shfl_down(mxy, off, 64));
    }
    __shared__ float sm[4][4];
    int lane = threadIdx.x & 63, wid = threadIdx.x >> 6;
    if (lane == 0){ sm[wid][0] = mnx; sm[wid][1] = mxx; sm[wid][2] = mny; sm[wid][3] = mxy; }
    __syncthreads();
    if (threadIdx.x == 0){
        int nw = blockDim.x >> 6;
        for (int w = 1; w < nw; ++w){
            mnx = fminf(mnx, sm[w][0]); mxx = fmaxf(mxx, sm[w][1]);
            mny = fminf(mny, sm[w][2]); mxy = fmaxf(mxy, sm[w][3]);
        }
        atomicMin(&mm[0], f2key(mnx));
        atomicMax(&mm[1], f2key(mxx));
        atomicMin(&mm[2], f2key(mny));
        atomicMax(&mm[3], f2key(mxy));
    }
}

__global__ void hist_kernel(const float4* __restrict__ x, const float4* __restrict__ y,
                            uint32_t* __restrict__ hist, const uint32_t* __restrict__ mm,
                            int n4){
    // broadcast scalar min/max (uniform loads)
    float mnx = key2f(mm[0]);
    float dx  = (key2f(mm[1]) - mnx) + 1e-8f;   // matches ref: (max - min) + EPS, f32
    float mny = key2f(mm[2]);
    float dy  = (key2f(mm[3]) - mny) + 1e-8f;
    int stride = gridDim.x * blockDim.x;
    for (int i = blockIdx.x * blockDim.x + threadIdx.x; i < n4; i += stride){
        float4 a = x[i];
        float4 b = y[i];
        float ax[4] = {a.x, a.y, a.z, a.w};
        float by[4] = {b.x, b.y, b.z, b.w};
        #pragma unroll
        for (int k = 0; k < 4; ++k){
            // replicate ref f32 math exactly: sub, IEEE div, *256 (exact), floor, clamp
            float xn = (ax[k] - mnx) / dx;
            float yn = (by[k] - mny) / dy;
            int ix = (int)floorf(xn * 256.0f);
            int iy = (int)floorf(yn * 256.0f);
            ix = ix < 0 ? 0 : (ix > 255 ? 255 : ix);
            iy = iy < 0 ? 0 : (iy > 255 ? 255 : iy);
            atomicAdd(&hist[(ix << 8) | iy], 1u);
        }
    }
}

__device__ double block_reduce_sum256(double v){
    __shared__ double sm[4];
    int lane = threadIdx.x & 63, wid = threadIdx.x >> 6;
    #pragma unroll
    for (int off = 32; off > 0; off >>= 1) v += __shfl_down(v, off, 64);
    __syncthreads();           // protect sm reuse across successive calls
    if (lane == 0) sm[wid] = v;
    __syncthreads();
    if (threadIdx.x == 0) v = sm[0] + sm[1] + sm[2] + sm[3];
    return v;                  // valid in thread 0 only
}

__global__ void finalize_kernel(const uint32_t* __restrict__ hist, float* __restrict__ out, int n){
    __shared__ double px[256], py[256];
    int t = threadIdx.x;
    const double invn = 1.0 / (double)n;
    uint32_t rs = 0, cs = 0;
    for (int j = 0; j < 256; ++j) rs += hist[(t << 8) | j];   // row t   -> p_x[t]
    for (int i = 0; i < 256; ++i) cs += hist[(i << 8) | t];   // col t   -> p_y[t]
    px[t] = (double)rs * invn;
    py[t] = (double)cs * invn;
    __syncthreads();
    double pxi = px[t];
    double mi = 0.0;
    for (int j = 0; j < 256; ++j){
        uint32_t c = hist[(t << 8) | j];
        if (c > 0u && pxi > 0.0 && py[j] > 0.0){
            double p = (double)c * invn;
            mi += p * log(p / (pxi * py[j]));
        }
    }
    double hx = px[t] * log(px[t] + 1e-8);   // -h_x contribution
    double hy = py[t] * log(py[t] + 1e-8);
    double mi_s = block_reduce_sum256(mi);
    double hx_s = block_reduce_sum256(hx);
    double hy_s = block_reduce_sum256(hy);
    if (t == 0){
        double h_x = -hx_s, h_y = -hy_s;
        double nmi = mi_s / (sqrt(h_x * h_y) + 1e-8);
        out[0] = (float)(-nmi);
    }
}

extern "C" void kernel_launch(void* const* d_in, const int* in_sizes, int n_in,
                              void* d_out, int out_size, void* d_ws, size_t ws_size,
                              hipStream_t stream){
    const float* x = (const float*)d_in[0];
    const float* y = (const float*)d_in[1];
    float* out = (float*)d_out;
    uint32_t* ws = (uint32_t*)d_ws;
    uint32_t* hist = ws;
    uint32_t* mm = ws + 65536;

    int n  = in_sizes[0];
    int n4 = n / 4;   // 4096*8192 divisible by 4

    hipMemsetAsync(hist, 0, 65536 * sizeof(uint32_t), stream);
    init_mm_kernel<<<1, 1, 0, stream>>>(mm);
    minmax_kernel<<<1024, 256, 0, stream>>>((const float4*)x, (const float4*)y, mm, n4);
    hist_kernel<<<2048, 256, 0, stream>>>((const float4*)x, (const float4*)y, hist, mm, n4);
    finalize_kernel<<<1, 256, 0, stream>>>(hist, out, n);
}

// Round 2
// 457.485 us; speedup vs baseline: 3.6152x; 3.6152x over previous
//
#include <hip/hip_runtime.h>
#include <stdint.h>
#include <math.h>

#define HIST_BINS   65536
#define HIST_WORDS8 16384          // uint32 words, 4 packed uint8 bins each (64 KB LDS)
#define NBLK_HIST   256
#define NTHR_HIST   1024

// ---------- float <-> monotonic uint key (for atomic min/max on floats) ----------
__device__ __forceinline__ uint32_t f2key(float f){
    uint32_t u = __float_as_uint(f);
    return (u & 0x80000000u) ? ~u : (u | 0x80000000u);
}
__device__ __forceinline__ float key2f(uint32_t k){
    uint32_t u = (k & 0x80000000u) ? (k ^ 0x80000000u) : ~k;
    return __uint_as_float(u);
}

// ws layout (uint32 words):
//   [0 .. 65535]           final uint32 joint histogram (256 KB)
//   [65536 .. 65539]       minmax keys: min_x, max_x, min_y, max_y
//   [65600 .. +256*16384]  per-block packed-uint8 partial histograms (16 MB)

__global__ void init_mm_kernel(uint32_t* __restrict__ mm){
    mm[0] = 0xFFFFFFFFu;  // +inf key for min_x
    mm[1] = 0u;           // -inf key for max_x
    mm[2] = 0xFFFFFFFFu;
    mm[3] = 0u;
}

__device__ __forceinline__ void mm4(float4 a, float& mn, float& mx){
    mn = fminf(mn, fminf(fminf(a.x, a.y), fminf(a.z, a.w)));
    mx = fmaxf(mx, fmaxf(fmaxf(a.x, a.y), fmaxf(a.z, a.w)));
}

__global__ void minmax_kernel(const float4* __restrict__ x, const float4* __restrict__ y,
                              uint32_t* __restrict__ mm, int n4){
    float mnx =  INFINITY, mxx = -INFINITY;
    float mny =  INFINITY, mxy = -INFINITY;
    int stride = gridDim.x * blockDim.x;
    int i = blockIdx.x * blockDim.x + threadIdx.x;
    // 4-way unrolled: 8 independent float4 loads in flight per iteration
    for (; i + 3 * stride < n4; i += 4 * stride){
        float4 a0 = x[i], a1 = x[i + stride], a2 = x[i + 2*stride], a3 = x[i + 3*stride];
        float4 b0 = y[i], b1 = y[i + stride], b2 = y[i + 2*stride], b3 = y[i + 3*stride];
        mm4(a0, mnx, mxx); mm4(a1, mnx, mxx); mm4(a2, mnx, mxx); mm4(a3, mnx, mxx);
        mm4(b0, mny, mxy); mm4(b1, mny, mxy); mm4(b2, mny, mxy); mm4(b3, mny, mxy);
    }
    for (; i < n4; i += stride){
        float4 a = x[i], b = y[i];
        mm4(a, mnx, mxx); mm4(b, mny, mxy);
    }
    // wave-64 shuffle reduce
    #pragma unroll
    for (int off = 32; off > 0; off >>= 1){
        mnx = fminf(mnx, __shfl_down(mnx, off, 64));
        mxx = fmaxf(mxx, __shfl_down(mxx, off, 64));
        mny = fminf(mny, __shfl_down(mny, off, 64));
        mxy = fmaxf(mxy, __shfl_down(mxy, off, 64));
    }
    __shared__ float sm[16][4];
    int lane = threadIdx.x & 63, wid = threadIdx.x >> 6;
    if (lane == 0){ sm[wid][0] = mnx; sm[wid][1] = mxx; sm[wid][2] = mny; sm[wid][3] = mxy; }
    __syncthreads();
    if (threadIdx.x == 0){
        int nw = blockDim.x >> 6;
        for (int w = 1; w < nw; ++w){
            mnx = fminf(mnx, sm[w][0]); mxx = fmaxf(mxx, sm[w][1]);
            mny = fminf(mny, sm[w][2]); mxy = fmaxf(mxy, sm[w][3]);
        }
        atomicMin(&mm[0], f2key(mnx));
        atomicMax(&mm[1], f2key(mxx));
        atomicMin(&mm[2], f2key(mny));
        atomicMax(&mm[3], f2key(mxy));
    }
}

__device__ __forceinline__ void bin_pair(float vx, float vy,
                                         float mnx, float sx, float mny, float sy,
                                         uint32_t* lh){
    int ix = (int)floorf((vx - mnx) * sx);
    int iy = (int)floorf((vy - mny) * sy);
    ix = ix < 0 ? 0 : (ix > 255 ? 255 : ix);
    iy = iy < 0 ? 0 : (iy > 255 ? 255 : iy);
    uint32_t bin = ((uint32_t)ix << 8) | (uint32_t)iy;
    atomicAdd(&lh[bin >> 2], 1u << ((bin & 3u) * 8u));
}

__global__ void __launch_bounds__(NTHR_HIST)
hist_kernel(const float4* __restrict__ x, const float4* __restrict__ y,
            const uint32_t* __restrict__ mm, uint32_t* __restrict__ out32,
            int n4, int atomic_flush){
    __shared__ uint32_t lh[HIST_WORDS8];   // 64 KB: 65536 uint8 bins packed 4/word
    for (int w = threadIdx.x; w < HIST_WORDS8; w += blockDim.x) lh[w] = 0u;
    __syncthreads();

    float mnx = key2f(mm[0]);
    float sx  = 256.0f / ((key2f(mm[1]) - mnx) + 1e-8f);
    float mny = key2f(mm[2]);
    float sy  = 256.0f / ((key2f(mm[3]) - mny) + 1e-8f);

    int stride = gridDim.x * blockDim.x;
    int i = blockIdx.x * blockDim.x + threadIdx.x;
    for (; i + stride < n4; i += 2 * stride){
        float4 a0 = x[i], a1 = x[i + stride];
        float4 b0 = y[i], b1 = y[i + stride];
        bin_pair(a0.x, b0.x, mnx, sx, mny, sy, lh);
        bin_pair(a0.y, b0.y, mnx, sx, mny, sy, lh);
        bin_pair(a0.z, b0.z, mnx, sx, mny, sy, lh);
        bin_pair(a0.w, b0.w, mnx, sx, mny, sy, lh);
        bin_pair(a1.x, b1.x, mnx, sx, mny, sy, lh);
        bin_pair(a1.y, b1.y, mnx, sx, mny, sy, lh);
        bin_pair(a1.z, b1.z, mnx, sx, mny, sy, lh);
        bin_pair(a1.w, b1.w, mnx, sx, mny, sy, lh);
    }
    for (; i < n4; i += stride){
        float4 a = x[i], b = y[i];
        bin_pair(a.x, b.x, mnx, sx, mny, sy, lh);
        bin_pair(a.y, b.y, mnx, sx, mny, sy, lh);
        bin_pair(a.z, b.z, mnx, sx, mny, sy, lh);
        bin_pair(a.w, b.w, mnx, sx, mny, sy, lh);
    }
    __syncthreads();

    if (!atomic_flush){
        // stream packed partial to ws (coalesced, no atomics)
        uint32_t* part = out32 + (size_t)blockIdx.x * HIST_WORDS8;
        for (int w = threadIdx.x; w < HIST_WORDS8; w += blockDim.x) part[w] = lh[w];
    } else {
        // fallback: global atomic flush of nonzero byte-counts
        for (int w = threadIdx.x; w < HIST_WORDS8; w += blockDim.x){
            uint32_t v = lh[w];
            if (v){
                uint32_t c0 = v & 255u, c1 = (v >> 8) & 255u, c2 = (v >> 16) & 255u, c3 = v >> 24;
                if (c0) atomicAdd(&out32[4*w + 0], c0);
                if (c1) atomicAdd(&out32[4*w + 1], c1);
                if (c2) atomicAdd(&out32[4*w + 2], c2);
                if (c3) atomicAdd(&out32[4*w + 3], c3);
            }
        }
    }
}

__global__ void reduce_kernel(const uint32_t* __restrict__ partials,
                              uint32_t* __restrict__ hist, int nparts){
    int w = blockIdx.x * blockDim.x + threadIdx.x;   // word index [0, 16384)
    uint32_t c0 = 0, c1 = 0, c2 = 0, c3 = 0;
    #pragma unroll 4
    for (int p = 0; p < nparts; ++p){
        uint32_t v = partials[(size_t)p * HIST_WORDS8 + w];
        c0 += v & 255u;
        c1 += (v >> 8) & 255u;
        c2 += (v >> 16) & 255u;
        c3 += v >> 24;
    }
    ((uint4*)hist)[w] = make_uint4(c0, c1, c2, c3);
}

__device__ double block_reduce_sum256(double v){
    __shared__ double sm[4];
    int lane = threadIdx.x & 63, wid = threadIdx.x >> 6;
    #pragma unroll
    for (int off = 32; off > 0; off >>= 1) v += __shfl_down(v, off, 64);
    __syncthreads();
    if (lane == 0) sm[wid] = v;
    __syncthreads();
    if (threadIdx.x == 0) v = sm[0] + sm[1] + sm[2] + sm[3];
    return v;  // valid in thread 0 only
}

__global__ void finalize_kernel(const uint32_t* __restrict__ hist, float* __restrict__ out, int n){
    __shared__ double px[256], py[256];
    int t = threadIdx.x;
    const double invn = 1.0 / (double)n;
    uint32_t rs = 0, cs = 0;
    for (int j = 0; j < 256; ++j) rs += hist[(t << 8) | j];
    for (int i = 0; i < 256; ++i) cs += hist[(i << 8) | t];
    px[t] = (double)rs * invn;
    py[t] = (double)cs * invn;
    __syncthreads();
    double pxi = px[t];
    double mi = 0.0;
    for (int j = 0; j < 256; ++j){
        uint32_t c = hist[(t << 8) | j];
        if (c > 0u && pxi > 0.0 && py[j] > 0.0){
            double p = (double)c * invn;
            mi += p * log(p / (pxi * py[j]));
        }
    }
    double hx = px[t] * log(px[t] + 1e-8);
    double hy = py[t] * log(py[t] + 1e-8);
    double mi_s = block_reduce_sum256(mi);
    double hx_s = block_reduce_sum256(hx);
    double hy_s = block_reduce_sum256(hy);
    if (t == 0){
        double h_x = -hx_s, h_y = -hy_s;
        double nmi = mi_s / (sqrt(h_x * h_y) + 1e-8);
        out[0] = (float)(-nmi);
    }
}

extern "C" void kernel_launch(void* const* d_in, const int* in_sizes, int n_in,
                              void* d_out, int out_size, void* d_ws, size_t ws_size,
                              hipStream_t stream){
    const float* x = (const float*)d_in[0];
    const float* y = (const float*)d_in[1];
    float* out = (float*)d_out;
    uint32_t* ws = (uint32_t*)d_ws;
    uint32_t* hist = ws;                       // 65536 uint32
    uint32_t* mm = ws + HIST_BINS;             // 4 uint32
    uint32_t* partials = ws + HIST_BINS + 64;  // 256 * 16384 uint32

    int n  = in_sizes[0];
    int n4 = n / 4;

    size_t need = ((size_t)HIST_BINS + 64 + (size_t)NBLK_HIST * HIST_WORDS8) * 4;
    int atomic_flush = (ws_size < need) ? 1 : 0;

    hipMemsetAsync(hist, 0, HIST_BINS * sizeof(uint32_t), stream);
    init_mm_kernel<<<1, 1, 0, stream>>>(mm);
    minmax_kernel<<<NBLK_HIST, NTHR_HIST, 0, stream>>>((const float4*)x, (const float4*)y, mm, n4);
    hist_kernel<<<NBLK_HIST, NTHR_HIST, 0, stream>>>((const float4*)x, (const float4*)y, mm,
                                                     atomic_flush ? hist : partials, n4, atomic_flush);
    if (!atomic_flush)
        reduce_kernel<<<HIST_WORDS8 / 256, 256, 0, stream>>>(partials, hist, NBLK_HIST);
    finalize_kernel<<<1, 256, 0, stream>>>(hist, out, n);
}

// Round 3
// 384.690 us; speedup vs baseline: 4.2993x; 1.1892x over previous
//
#include <hip/hip_runtime.h>
#include <stdint.h>
#include <math.h>

#define HIST_BINS   65536
#define HIST_WORDS8 16384          // uint32 words, 4 packed uint8 bins each (64 KB LDS)
#define NTHR_HIST   1024

// ---------- float <-> monotonic uint key (for atomic min/max on floats) ----------
__device__ __forceinline__ uint32_t f2key(float f){
    uint32_t u = __float_as_uint(f);
    return (u & 0x80000000u) ? ~u : (u | 0x80000000u);
}
__device__ __forceinline__ float key2f(uint32_t k){
    uint32_t u = (k & 0x80000000u) ? (k ^ 0x80000000u) : ~k;
    return __uint_as_float(u);
}

// ws layout (uint32 words):
//   [0 .. 65535]           final uint32 joint histogram (256 KB)
//   [65536 .. 65539]       minmax keys: min_x, max_x, min_y, max_y
//   [65600 ...]            per-block packed-uint8 partial histograms (nblk * 64 KB)

__global__ void init_mm_kernel(uint32_t* __restrict__ mm){
    mm[0] = 0xFFFFFFFFu;  // +inf key for min_x
    mm[1] = 0u;           // -inf key for max_x
    mm[2] = 0xFFFFFFFFu;
    mm[3] = 0u;
}

__device__ __forceinline__ void mm4(float4 a, float& mn, float& mx){
    mn = fminf(mn, fminf(fminf(a.x, a.y), fminf(a.z, a.w)));
    mx = fmaxf(mx, fmaxf(fmaxf(a.x, a.y), fmaxf(a.z, a.w)));
}

__global__ void __launch_bounds__(NTHR_HIST)
minmax_kernel(const float4* __restrict__ x, const float4* __restrict__ y,
              uint32_t* __restrict__ mm, int n4){
    float mnx =  INFINITY, mxx = -INFINITY;
    float mny =  INFINITY, mxy = -INFINITY;
    int stride = gridDim.x * blockDim.x;
    int i = blockIdx.x * blockDim.x + threadIdx.x;
    // 4-way unrolled: 8 independent float4 loads in flight per iteration
    for (; i + 3 * stride < n4; i += 4 * stride){
        float4 a0 = x[i], a1 = x[i + stride], a2 = x[i + 2*stride], a3 = x[i + 3*stride];
        float4 b0 = y[i], b1 = y[i + stride], b2 = y[i + 2*stride], b3 = y[i + 3*stride];
        mm4(a0, mnx, mxx); mm4(a1, mnx, mxx); mm4(a2, mnx, mxx); mm4(a3, mnx, mxx);
        mm4(b0, mny, mxy); mm4(b1, mny, mxy); mm4(b2, mny, mxy); mm4(b3, mny, mxy);
    }
    for (; i < n4; i += stride){
        float4 a = x[i], b = y[i];
        mm4(a, mnx, mxx); mm4(b, mny, mxy);
    }
    #pragma unroll
    for (int off = 32; off > 0; off >>= 1){
        mnx = fminf(mnx, __shfl_down(mnx, off, 64));
        mxx = fmaxf(mxx, __shfl_down(mxx, off, 64));
        mny = fminf(mny, __shfl_down(mny, off, 64));
        mxy = fmaxf(mxy, __shfl_down(mxy, off, 64));
    }
    __shared__ float sm[16][4];
    int lane = threadIdx.x & 63, wid = threadIdx.x >> 6;
    if (lane == 0){ sm[wid][0] = mnx; sm[wid][1] = mxx; sm[wid][2] = mny; sm[wid][3] = mxy; }
    __syncthreads();
    if (threadIdx.x == 0){
        int nw = blockDim.x >> 6;
        for (int w = 1; w < nw; ++w){
            mnx = fminf(mnx, sm[w][0]); mxx = fmaxf(mxx, sm[w][1]);
            mny = fminf(mny, sm[w][2]); mxy = fmaxf(mxy, sm[w][3]);
        }
        atomicMin(&mm[0], f2key(mnx));
        atomicMax(&mm[1], f2key(mxx));
        atomicMin(&mm[2], f2key(mny));
        atomicMax(&mm[3], f2key(mxy));
    }
}

__device__ __forceinline__ void bin_pair(float vx, float vy,
                                         float mnx, float sx, float mny, float sy,
                                         uint32_t* lh){
    int ix = (int)floorf((vx - mnx) * sx);
    int iy = (int)floorf((vy - mny) * sy);
    ix = ix < 0 ? 0 : (ix > 255 ? 255 : ix);
    iy = iy < 0 ? 0 : (iy > 255 ? 255 : iy);
    uint32_t bin = ((uint32_t)ix << 8) | (uint32_t)iy;
    atomicAdd(&lh[bin >> 2], 1u << ((bin & 3u) * 8u));
}

__device__ __forceinline__ void bin4(float4 a, float4 b,
                                     float mnx, float sx, float mny, float sy,
                                     uint32_t* lh){
    bin_pair(a.x, b.x, mnx, sx, mny, sy, lh);
    bin_pair(a.y, b.y, mnx, sx, mny, sy, lh);
    bin_pair(a.z, b.z, mnx, sx, mny, sy, lh);
    bin_pair(a.w, b.w, mnx, sx, mny, sy, lh);
}

__global__ void __launch_bounds__(NTHR_HIST)
hist_kernel(const float4* __restrict__ x, const float4* __restrict__ y,
            const uint32_t* __restrict__ mm, uint32_t* __restrict__ out32,
            int n4, int atomic_flush){
    __shared__ uint32_t lh[HIST_WORDS8];   // 64 KB: 65536 uint8 bins packed 4/word
    for (int w = threadIdx.x; w < HIST_WORDS8; w += blockDim.x) lh[w] = 0u;
    __syncthreads();

    float mnx = key2f(mm[0]);
    float sx  = 256.0f / ((key2f(mm[1]) - mnx) + 1e-8f);
    float mny = key2f(mm[2]);
    float sy  = 256.0f / ((key2f(mm[3]) - mny) + 1e-8f);

    int stride = gridDim.x * blockDim.x;
    int i = blockIdx.x * blockDim.x + threadIdx.x;
    // 4-way unrolled: 8 independent float4 loads in flight
    for (; i + 3 * stride < n4; i += 4 * stride){
        float4 a0 = x[i], a1 = x[i + stride], a2 = x[i + 2*stride], a3 = x[i + 3*stride];
        float4 b0 = y[i], b1 = y[i + stride], b2 = y[i + 2*stride], b3 = y[i + 3*stride];
        bin4(a0, b0, mnx, sx, mny, sy, lh);
        bin4(a1, b1, mnx, sx, mny, sy, lh);
        bin4(a2, b2, mnx, sx, mny, sy, lh);
        bin4(a3, b3, mnx, sx, mny, sy, lh);
    }
    for (; i < n4; i += stride){
        float4 a = x[i], b = y[i];
        bin4(a, b, mnx, sx, mny, sy, lh);
    }
    __syncthreads();

    if (!atomic_flush){
        uint32_t* part = out32 + (size_t)blockIdx.x * HIST_WORDS8;
        for (int w = threadIdx.x; w < HIST_WORDS8; w += blockDim.x) part[w] = lh[w];
    } else {
        for (int w = threadIdx.x; w < HIST_WORDS8; w += blockDim.x){
            uint32_t v = lh[w];
            if (v){
                uint32_t c0 = v & 255u, c1 = (v >> 8) & 255u, c2 = (v >> 16) & 255u, c3 = v >> 24;
                if (c0) atomicAdd(&out32[4*w + 0], c0);
                if (c1) atomicAdd(&out32[4*w + 1], c1);
                if (c2) atomicAdd(&out32[4*w + 2], c2);
                if (c3) atomicAdd(&out32[4*w + 3], c3);
            }
        }
    }
}

// 256 blocks x 256 threads: block b sums words [b*64, b*64+64) over all partials.
// Threads: 4 partial-groups (g) x 64 words (wl).
__global__ void reduce_kernel(const uint32_t* __restrict__ partials,
                              uint32_t* __restrict__ hist, int nparts){
    __shared__ uint32_t sm[4][64][4];
    int wl = threadIdx.x & 63;
    int g  = threadIdx.x >> 6;
    int w  = blockIdx.x * 64 + wl;
    int per = nparts >> 2;
    uint32_t c0 = 0, c1 = 0, c2 = 0, c3 = 0;
    const uint32_t* p = partials + (size_t)(g * per) * HIST_WORDS8 + w;
    for (int k = 0; k < per; ++k){
        uint32_t v = p[(size_t)k * HIST_WORDS8];
        c0 += v & 255u; c1 += (v >> 8) & 255u; c2 += (v >> 16) & 255u; c3 += v >> 24;
    }
    sm[g][wl][0] = c0; sm[g][wl][1] = c1; sm[g][wl][2] = c2; sm[g][wl][3] = c3;
    __syncthreads();
    if (g == 0){
        uint4 r;
        r.x = sm[0][wl][0] + sm[1][wl][0] + sm[2][wl][0] + sm[3][wl][0];
        r.y = sm[0][wl][1] + sm[1][wl][1] + sm[2][wl][1] + sm[3][wl][1];
        r.z = sm[0][wl][2] + sm[1][wl][2] + sm[2][wl][2] + sm[3][wl][2];
        r.w = sm[0][wl][3] + sm[1][wl][3] + sm[2][wl][3] + sm[3][wl][3];
        ((uint4*)hist)[w] = r;
    }
}

__device__ double bsum1024(double v, double* red, int t){
    #pragma unroll
    for (int off = 32; off > 0; off >>= 1) v += __shfl_down(v, off, 64);
    __syncthreads();
    if ((t & 63) == 0) red[t >> 6] = v;
    __syncthreads();
    if (t == 0){
        double s = 0.0;
        for (int w = 0; w < 16; ++w) s += red[w];
        v = s;
    }
    return v;  // valid in thread 0 only
}

__global__ void __launch_bounds__(1024)
finalize_kernel(const uint32_t* __restrict__ hist, float* __restrict__ out, int n){
    __shared__ uint32_t rsum[256];      // row sums  (p_x counts)
    __shared__ uint32_t csum4[4][256];  // partial col sums
    __shared__ uint32_t csum[256];      // col sums  (p_y counts)
    __shared__ double red[16];
    int t = threadIdx.x;

    // Phase A: row sums. 4 threads per row, 16 uint4 (64 words) each, coalesced.
    {
        int r = t >> 2, q = t & 3;
        const uint4* hp = (const uint4*)(hist + r * 256 + q * 64);
        uint32_t s = 0;
        #pragma unroll
        for (int k = 0; k < 16; ++k){
            uint4 v = hp[k];
            s += v.x + v.y + v.z + v.w;
        }
        s += __shfl_down(s, 2, 64);   // q-groups are adjacent lanes
        s += __shfl_down(s, 1, 64);
        if (q == 0) rsum[r] = s;
    }
    // Phase B: col sums. c = t&255 (coalesced across lanes), 4 row-groups.
    {
        int c = t & 255, g = t >> 8;
        const uint32_t* hp = hist + g * 64 * 256 + c;
        uint32_t s = 0;
        #pragma unroll 8
        for (int r = 0; r < 64; ++r) s += hp[r * 256];
        csum4[g][c] = s;
    }
    __syncthreads();
    if (t < 256) csum[t] = csum4[0][t] + csum4[1][t] + csum4[2][t] + csum4[3][t];
    __syncthreads();

    const double invn = 1.0 / (double)n;
    const double dn = (double)n;

    // MI: thread handles column c = t&255, rows 4k + (t>>8). Coalesced hist reads,
    // f32 log (rel err ~1e-7 on log-values ~0.04 -> MI err <1e-8), f64 accumulation.
    double mi = 0.0;
    {
        int c = t & 255, rb = t >> 8;
        double cs = (double)csum[c];
        for (int k = 0; k < 64; ++k){
            int r = k * 4 + rb;
            uint32_t cnt = hist[r * 256 + c];
            if (cnt){
                double rs = (double)rsum[r];
                double ratio = ((double)cnt * dn) / (rs * cs);
                mi += (double)cnt * (double)logf((float)ratio);
            }
        }
        mi *= invn;
    }
    // Entropy terms (256 double logs, cheap)
    double hx = 0.0, hy = 0.0;
    if (t < 256){
        double px = (double)rsum[t] * invn;
        double py = (double)csum[t] * invn;
        hx = px * log(px + 1e-8);
        hy = py * log(py + 1e-8);
    }
    double mi_s = bsum1024(mi, red, t);
    double hx_s = bsum1024(hx, red, t);
    double hy_s = bsum1024(hy, red, t);
    if (t == 0){
        double h_x = -hx_s, h_y = -hy_s;
        double nmi = mi_s / (sqrt(h_x * h_y) + 1e-8);
        out[0] = (float)(-nmi);
    }
}

extern "C" void kernel_launch(void* const* d_in, const int* in_sizes, int n_in,
                              void* d_out, int out_size, void* d_ws, size_t ws_size,
                              hipStream_t stream){
    const float* x = (const float*)d_in[0];
    const float* y = (const float*)d_in[1];
    float* out = (float*)d_out;
    uint32_t* ws = (uint32_t*)d_ws;
    uint32_t* hist = ws;                       // 65536 uint32
    uint32_t* mm = ws + HIST_BINS;             // 4 uint32
    uint32_t* partials = ws + HIST_BINS + 64;  // nblk * 16384 uint32

    int n  = in_sizes[0];
    int n4 = n / 4;

    // choose histogram block count by available scratch (constant across calls)
    size_t need512 = ((size_t)HIST_BINS + 64 + (size_t)512 * HIST_WORDS8) * 4;
    size_t need256 = ((size_t)HIST_BINS + 64 + (size_t)256 * HIST_WORDS8) * 4;
    int nblk, atomic_flush;
    if (ws_size >= need512)      { nblk = 512; atomic_flush = 0; }
    else if (ws_size >= need256) { nblk = 256; atomic_flush = 0; }
    else                         { nblk = 512; atomic_flush = 1; }

    if (atomic_flush)
        hipMemsetAsync(hist, 0, HIST_BINS * sizeof(uint32_t), stream);
    init_mm_kernel<<<1, 1, 0, stream>>>(mm);
    minmax_kernel<<<512, NTHR_HIST, 0, stream>>>((const float4*)x, (const float4*)y, mm, n4);
    hist_kernel<<<nblk, NTHR_HIST, 0, stream>>>((const float4*)x, (const float4*)y, mm,
                                                atomic_flush ? hist : partials, n4, atomic_flush);
    if (!atomic_flush)
        reduce_kernel<<<HIST_WORDS8 / 64, 256, 0, stream>>>(partials, hist, nblk);
    finalize_kernel<<<1, 1024, 0, stream>>>(hist, out, n);
}

// Round 4
// 367.949 us; speedup vs baseline: 4.4949x; 1.0455x over previous
//
#include <hip/hip_runtime.h>
#include <stdint.h>
#include <math.h>

#define HIST_BINS   65536
#define HIST_WORDS8 16384          // uint32 words, 4 packed uint8 bins each (64 KB LDS)
#define NTHR_HIST   1024

// ---------- float <-> monotonic uint key (for atomic min/max on floats) ----------
__device__ __forceinline__ uint32_t f2key(float f){
    uint32_t u = __float_as_uint(f);
    return (u & 0x80000000u) ? ~u : (u | 0x80000000u);
}
__device__ __forceinline__ float key2f(uint32_t k){
    uint32_t u = (k & 0x80000000u) ? (k ^ 0x80000000u) : ~k;
    return __uint_as_float(u);
}

// ws layout (uint32 words):
//   [0 .. 65535]           final uint32 joint histogram (256 KB)
//   [65536 .. 65539]       minmax keys: min_x, max_x, min_y, max_y
//   [65600 ...]            per-block packed-uint8 partial histograms (nblk * 64 KB)

__global__ void init_mm_kernel(uint32_t* __restrict__ mm){
    mm[0] = 0xFFFFFFFFu;  // +inf key for min_x
    mm[1] = 0u;           // -inf key for max_x
    mm[2] = 0xFFFFFFFFu;
    mm[3] = 0u;
}

__device__ __forceinline__ void mm4(float4 a, float& mn, float& mx){
    mn = fminf(mn, fminf(fminf(a.x, a.y), fminf(a.z, a.w)));
    mx = fmaxf(mx, fmaxf(fmaxf(a.x, a.y), fmaxf(a.z, a.w)));
}

// blocks [0, nblk_per) scan x; blocks [nblk_per, 2*nblk_per) scan y.
// 8 independent float4 loads in flight per thread; exactly 4 main iterations.
__global__ void __launch_bounds__(1024)
minmax_kernel(const float4* __restrict__ x, const float4* __restrict__ y,
              uint32_t* __restrict__ mm, int n4, int nblk_per){
    int isy = (blockIdx.x >= (unsigned)nblk_per) ? 1 : 0;
    const float4* __restrict__ src = isy ? y : x;
    int bid = blockIdx.x - isy * nblk_per;
    float mn = INFINITY, mx = -INFINITY;
    int stride = nblk_per * blockDim.x;
    int i = bid * blockDim.x + threadIdx.x;
    for (; i + 7 * stride < n4; i += 8 * stride){
        float4 v0 = src[i];
        float4 v1 = src[i +     stride];
        float4 v2 = src[i + 2 * stride];
        float4 v3 = src[i + 3 * stride];
        float4 v4 = src[i + 4 * stride];
        float4 v5 = src[i + 5 * stride];
        float4 v6 = src[i + 6 * stride];
        float4 v7 = src[i + 7 * stride];
        mm4(v0, mn, mx); mm4(v1, mn, mx); mm4(v2, mn, mx); mm4(v3, mn, mx);
        mm4(v4, mn, mx); mm4(v5, mn, mx); mm4(v6, mn, mx); mm4(v7, mn, mx);
    }
    for (; i < n4; i += stride) mm4(src[i], mn, mx);

    #pragma unroll
    for (int off = 32; off > 0; off >>= 1){
        mn = fminf(mn, __shfl_down(mn, off, 64));
        mx = fmaxf(mx, __shfl_down(mx, off, 64));
    }
    __shared__ float smn[16], smx[16];
    int lane = threadIdx.x & 63, wid = threadIdx.x >> 6;
    if (lane == 0){ smn[wid] = mn; smx[wid] = mx; }
    __syncthreads();
    if (threadIdx.x == 0){
        int nw = blockDim.x >> 6;
        for (int w = 1; w < nw; ++w){
            mn = fminf(mn, smn[w]); mx = fmaxf(mx, smx[w]);
        }
        atomicMin(&mm[isy * 2 + 0], f2key(mn));
        atomicMax(&mm[isy * 2 + 1], f2key(mx));
    }
}

__device__ __forceinline__ void bin_pair(float vx, float vy,
                                         float mnx, float sx, float mny, float sy,
                                         uint32_t* lh){
    int ix = (int)floorf((vx - mnx) * sx);
    int iy = (int)floorf((vy - mny) * sy);
    ix = ix < 0 ? 0 : (ix > 255 ? 255 : ix);
    iy = iy < 0 ? 0 : (iy > 255 ? 255 : iy);
    uint32_t bin = ((uint32_t)ix << 8) | (uint32_t)iy;
    atomicAdd(&lh[bin >> 2], 1u << ((bin & 3u) * 8u));
}

__device__ __forceinline__ void bin4(float4 a, float4 b,
                                     float mnx, float sx, float mny, float sy,
                                     uint32_t* lh){
    bin_pair(a.x, b.x, mnx, sx, mny, sy, lh);
    bin_pair(a.y, b.y, mnx, sx, mny, sy, lh);
    bin_pair(a.z, b.z, mnx, sx, mny, sy, lh);
    bin_pair(a.w, b.w, mnx, sx, mny, sy, lh);
}

__global__ void __launch_bounds__(NTHR_HIST)
hist_kernel(const float4* __restrict__ x, const float4* __restrict__ y,
            const uint32_t* __restrict__ mm, uint32_t* __restrict__ out32,
            int n4, int atomic_flush){
    __shared__ uint32_t lh[HIST_WORDS8];   // 64 KB: 65536 uint8 bins packed 4/word
    for (int w = threadIdx.x; w < HIST_WORDS8; w += blockDim.x) lh[w] = 0u;
    __syncthreads();

    float mnx = key2f(mm[0]);
    float sx  = 256.0f / ((key2f(mm[1]) - mnx) + 1e-8f);
    float mny = key2f(mm[2]);
    float sy  = 256.0f / ((key2f(mm[3]) - mny) + 1e-8f);

    int stride = gridDim.x * blockDim.x;
    int i = blockIdx.x * blockDim.x + threadIdx.x;
    for (; i + 3 * stride < n4; i += 4 * stride){
        float4 a0 = x[i], a1 = x[i + stride], a2 = x[i + 2*stride], a3 = x[i + 3*stride];
        float4 b0 = y[i], b1 = y[i + stride], b2 = y[i + 2*stride], b3 = y[i + 3*stride];
        bin4(a0, b0, mnx, sx, mny, sy, lh);
        bin4(a1, b1, mnx, sx, mny, sy, lh);
        bin4(a2, b2, mnx, sx, mny, sy, lh);
        bin4(a3, b3, mnx, sx, mny, sy, lh);
    }
    for (; i < n4; i += stride){
        float4 a = x[i], b = y[i];
        bin4(a, b, mnx, sx, mny, sy, lh);
    }
    __syncthreads();

    if (!atomic_flush){
        uint32_t* part = out32 + (size_t)blockIdx.x * HIST_WORDS8;
        for (int w = threadIdx.x; w < HIST_WORDS8; w += blockDim.x) part[w] = lh[w];
    } else {
        for (int w = threadIdx.x; w < HIST_WORDS8; w += blockDim.x){
            uint32_t v = lh[w];
            if (v){
                uint32_t c0 = v & 255u, c1 = (v >> 8) & 255u, c2 = (v >> 16) & 255u, c3 = v >> 24;
                if (c0) atomicAdd(&out32[4*w + 0], c0);
                if (c1) atomicAdd(&out32[4*w + 1], c1);
                if (c2) atomicAdd(&out32[4*w + 2], c2);
                if (c3) atomicAdd(&out32[4*w + 3], c3);
            }
        }
    }
}

// 256 blocks x 1024 threads. Block b covers word-quads [b*16, b*16+16)
// (quad = uint4 = 4 packed words = 16 bins). Thread: ql = t&15 (quad within
// block, consecutive lanes -> consecutive uint4s), g = t>>4 (64 partial-groups
// of per = nparts/64 each; all loads independent -> deep ILP).
__global__ void __launch_bounds__(1024)
reduce_kernel(const uint32_t* __restrict__ partials, uint32_t* __restrict__ hist,
              int nparts){
    __shared__ uint32_t sm[64][16][16];  // [g][k][ql], 64 KB
    int t = threadIdx.x;
    int ql = t & 15, g = t >> 4;
    int per = nparts >> 6;   // 8 (nblk=512) or 4 (nblk=256)
    uint32_t c[16];
    #pragma unroll
    for (int k = 0; k < 16; ++k) c[k] = 0;
    const uint4* base = (const uint4*)partials;
    size_t qoff = (size_t)blockIdx.x * 16 + ql;
    #pragma unroll 8
    for (int j = 0; j < per; ++j){
        uint4 v = base[(size_t)(g * per + j) * (HIST_WORDS8 / 4) + qoff];
        c[ 0] += v.x & 255u; c[ 1] += (v.x >> 8) & 255u; c[ 2] += (v.x >> 16) & 255u; c[ 3] += v.x >> 24;
        c[ 4] += v.y & 255u; c[ 5] += (v.y >> 8) & 255u; c[ 6] += (v.y >> 16) & 255u; c[ 7] += v.y >> 24;
        c[ 8] += v.z & 255u; c[ 9] += (v.z >> 8) & 255u; c[10] += (v.z >> 16) & 255u; c[11] += v.z >> 24;
        c[12] += v.w & 255u; c[13] += (v.w >> 8) & 255u; c[14] += (v.w >> 16) & 255u; c[15] += v.w >> 24;
    }
    #pragma unroll
    for (int k = 0; k < 16; ++k) sm[g][k][ql] = c[k];
    __syncthreads();
    if (t < 256){
        int q2 = t & 15;      // quad within block
        int k  = t >> 4;      // bin within quad
        uint32_t s = 0;
        #pragma unroll 8
        for (int gg = 0; gg < 64; ++gg) s += sm[gg][k][q2];
        hist[((size_t)blockIdx.x * 16 + q2) * 16 + k] = s;
    }
}

__device__ double bsum1024(double v, double* red, int t){
    #pragma unroll
    for (int off = 32; off > 0; off >>= 1) v += __shfl_down(v, off, 64);
    __syncthreads();
    if ((t & 63) == 0) red[t >> 6] = v;
    __syncthreads();
    if (t == 0){
        double s = 0.0;
        for (int w = 0; w < 16; ++w) s += red[w];
        v = s;
    }
    return v;  // valid in thread 0 only
}

__global__ void __launch_bounds__(1024)
finalize_kernel(const uint32_t* __restrict__ hist, float* __restrict__ out, int n){
    __shared__ uint32_t rsum[256];      // row sums  (p_x counts)
    __shared__ uint32_t csum4[4][256];  // partial col sums
    __shared__ uint32_t csum[256];      // col sums  (p_y counts)
    __shared__ double red[16];
    int t = threadIdx.x;

    // Phase A: row sums. 4 threads per row, 16 uint4 (64 words) each, coalesced.
    {
        int r = t >> 2, q = t & 3;
        const uint4* hp = (const uint4*)(hist + r * 256 + q * 64);
        uint32_t s = 0;
        #pragma unroll
        for (int k = 0; k < 16; ++k){
            uint4 v = hp[k];
            s += v.x + v.y + v.z + v.w;
        }
        s += __shfl_down(s, 2, 64);
        s += __shfl_down(s, 1, 64);
        if (q == 0) rsum[r] = s;
    }
    // Phase B: col sums. c = t&255 (coalesced across lanes), 4 row-groups.
    {
        int c = t & 255, g = t >> 8;
        const uint32_t* hp = hist + g * 64 * 256 + c;
        uint32_t s = 0;
        #pragma unroll 8
        for (int r = 0; r < 64; ++r) s += hp[r * 256];
        csum4[g][c] = s;
    }
    __syncthreads();
    if (t < 256) csum[t] = csum4[0][t] + csum4[1][t] + csum4[2][t] + csum4[3][t];
    __syncthreads();

    const double invn = 1.0 / (double)n;
    const double dn = (double)n;

    // MI: thread handles column c = t&255, rows 4k + (t>>8). Coalesced hist reads,
    // f32 log (rel err ~1e-7 on log-values ~0.04 -> MI err <1e-8), f64 accumulation.
    double mi = 0.0;
    {
        int c = t & 255, rb = t >> 8;
        double cs = (double)csum[c];
        for (int k = 0; k < 64; ++k){
            int r = k * 4 + rb;
            uint32_t cnt = hist[r * 256 + c];
            if (cnt){
                double rs = (double)rsum[r];
                double ratio = ((double)cnt * dn) / (rs * cs);
                mi += (double)cnt * (double)logf((float)ratio);
            }
        }
        mi *= invn;
    }
    double hx = 0.0, hy = 0.0;
    if (t < 256){
        double px = (double)rsum[t] * invn;
        double py = (double)csum[t] * invn;
        hx = px * log(px + 1e-8);
        hy = py * log(py + 1e-8);
    }
    double mi_s = bsum1024(mi, red, t);
    double hx_s = bsum1024(hx, red, t);
    double hy_s = bsum1024(hy, red, t);
    if (t == 0){
        double h_x = -hx_s, h_y = -hy_s;
        double nmi = mi_s / (sqrt(h_x * h_y) + 1e-8);
        out[0] = (float)(-nmi);
    }
}

extern "C" void kernel_launch(void* const* d_in, const int* in_sizes, int n_in,
                              void* d_out, int out_size, void* d_ws, size_t ws_size,
                              hipStream_t stream){
    const float* x = (const float*)d_in[0];
    const float* y = (const float*)d_in[1];
    float* out = (float*)d_out;
    uint32_t* ws = (uint32_t*)d_ws;
    uint32_t* hist = ws;                       // 65536 uint32
    uint32_t* mm = ws + HIST_BINS;             // 4 uint32
    uint32_t* partials = ws + HIST_BINS + 64;  // nblk * 16384 uint32

    int n  = in_sizes[0];
    int n4 = n / 4;

    size_t need512 = ((size_t)HIST_BINS + 64 + (size_t)512 * HIST_WORDS8) * 4;
    size_t need256 = ((size_t)HIST_BINS + 64 + (size_t)256 * HIST_WORDS8) * 4;
    int nblk, atomic_flush;
    if (ws_size >= need512)      { nblk = 512; atomic_flush = 0; }
    else if (ws_size >= need256) { nblk = 256; atomic_flush = 0; }
    else                         { nblk = 512; atomic_flush = 1; }

    if (atomic_flush)
        hipMemsetAsync(hist, 0, HIST_BINS * sizeof(uint32_t), stream);
    init_mm_kernel<<<1, 1, 0, stream>>>(mm);
    minmax_kernel<<<512, 1024, 0, stream>>>((const float4*)x, (const float4*)y, mm, n4, 256);
    hist_kernel<<<nblk, NTHR_HIST, 0, stream>>>((const float4*)x, (const float4*)y, mm,
                                                atomic_flush ? hist : partials, n4, atomic_flush);
    if (!atomic_flush)
        reduce_kernel<<<256, 1024, 0, stream>>>(partials, hist, nblk);
    finalize_kernel<<<1, 1024, 0, stream>>>(hist, out, n);
}